// Round 14
// baseline (33.899 us; speedup 1.0000x reference)
//
#include <hip/hip_runtime.h>

#define B_N 8192
#define K_CL 64
#define SEG 8
#define CAP_SEG 48
#define LCAP (SEG * CAP_SEG)   /* 384 max staged per cluster */
#define NPAIR 2016
#define INF_F 3.0e38f

// R14 theory: the ~21us gather residual (invariant across 3 structures) is
// cold-HBM miss latency for 96KB of inputs issued by only 64 blocks
// (inter-replay 268MB poison fills flush L2/L3). Fix = more miss-issue
// parallelism: 64x8 grid, each block scans 1024 points (12KB).
// Segmented lists, no atomics, no memset, deterministic order.
// ws: lists float2[64*8*48] (192KB) | cnts int[512] | hinges float[64*64]

__global__ __launch_bounds__(256) void gather_kernel(
    const int* __restrict__ labels, const float* __restrict__ coords,
    float2* __restrict__ lists, int* __restrict__ cnts) {
    int c = blockIdx.x, q = blockIdx.y;
    int tid = threadIdx.x, lane = tid & 63, wave = tid >> 6;
    __shared__ int wsum[4];

    // unconditional preload: 1 int4 (4 labels) + 2 float4 (4 points)
    int v4 = q * 256 + tid;
    int4   lb = reinterpret_cast<const int4*>(labels)[v4];
    float4 ca = reinterpret_cast<const float4*>(coords)[2 * v4];
    float4 cb = reinterpret_cast<const float4*>(coords)[2 * v4 + 1];

    int mcnt = (lb.x == c) + (lb.y == c) + (lb.z == c) + (lb.w == c);

    // block exclusive scan (wave shfl_up + 4-wave LDS combine)
    int incl = mcnt;
#pragma unroll
    for (int d = 1; d < 64; d <<= 1) {
        int u = __shfl_up(incl, d, 64);
        if (lane >= d) incl += u;
    }
    if (lane == 63) wsum[wave] = incl;
    __syncthreads();
    int wbase = 0;
#pragma unroll
    for (int w = 0; w < 4; ++w) wbase += (w < wave) ? wsum[w] : 0;
    int base = wbase + incl - mcnt;
    if (tid == 255) cnts[c * SEG + q] = min(base + mcnt, CAP_SEG);

    // write loop: registers + stores only
    float2* seg = lists + (c * SEG + q) * CAP_SEG;
    int pos = base;
    if (lb.x == c) { if (pos < CAP_SEG) seg[pos] = make_float2(ca.x, ca.y); pos++; }
    if (lb.y == c) { if (pos < CAP_SEG) seg[pos] = make_float2(ca.z, ca.w); pos++; }
    if (lb.z == c) { if (pos < CAP_SEG) seg[pos] = make_float2(cb.x, cb.y); pos++; }
    if (lb.w == c) { if (pos < CAP_SEG) seg[pos] = make_float2(cb.z, cb.w); pos++; }
}

__global__ __launch_bounds__(256) void pair_min_kernel(
    const float2* __restrict__ lists, const int* __restrict__ cnts,
    float* __restrict__ hinges) {
    int ci = blockIdx.x, cj = blockIdx.y;
    if (ci >= cj) return;                 // uniform per block
    int tid = threadIdx.x;

    // 8-segment prefix (redundant per thread, trivial)
    int cI[SEG + 1], cJ[SEG + 1];
    cI[0] = 0; cJ[0] = 0;
#pragma unroll
    for (int s = 0; s < SEG; ++s) {
        cI[s + 1] = cI[s] + cnts[ci * SEG + s];
        cJ[s + 1] = cJ[s] + cnts[cj * SEG + s];
    }
    int nI = cI[SEG], nJ = cJ[SEG];

    __shared__ float2 ipt[LCAP], jpt[LCAP];
#pragma unroll
    for (int s = 0; s < SEG; ++s) {
        int nqi = cI[s + 1] - cI[s];
        if (tid < nqi) ipt[cI[s] + tid] = lists[(ci * SEG + s) * CAP_SEG + tid];
        int nqj = cJ[s + 1] - cJ[s];
        if (tid < nqj) jpt[cJ[s] + tid] = lists[(cj * SEG + s) * CAP_SEG + tid];
    }
    __syncthreads();

    // 2 threads per i-point, 4-accumulator unrolled j-half
    int half = (nJ + 1) >> 1;
    int j0 = (tid & 1) ? half : 0;
    int j1 = (tid & 1) ? nJ : half;
    float m0 = INF_F, m1 = INF_F, m2 = INF_F, m3 = INF_F;
    for (int i = tid >> 1; i < nI; i += 128) {
        float2 pi = ipt[i];
        int j = j0;
        for (; j + 3 < j1; j += 4) {
            float2 a = jpt[j], b = jpt[j+1], c = jpt[j+2], d = jpt[j+3];
            float dx0 = pi.x - a.x, dy0 = pi.y - a.y;
            float dx1 = pi.x - b.x, dy1 = pi.y - b.y;
            float dx2 = pi.x - c.x, dy2 = pi.y - c.y;
            float dx3 = pi.x - d.x, dy3 = pi.y - d.y;
            m0 = fminf(m0, dx0*dx0 + dy0*dy0);
            m1 = fminf(m1, dx1*dx1 + dy1*dy1);
            m2 = fminf(m2, dx2*dx2 + dy2*dy2);
            m3 = fminf(m3, dx3*dx3 + dy3*dy3);
        }
        for (; j < j1; ++j) {
            float dx = pi.x - jpt[j].x, dy = pi.y - jpt[j].y;
            m0 = fminf(m0, dx*dx + dy*dy);
        }
    }
    float myMin = fminf(fminf(m0, m1), fminf(m2, m3));

    for (int off = 32; off > 0; off >>= 1)
        myMin = fminf(myMin, __shfl_down(myMin, off, 64));
    __shared__ float wmin[4];
    int wave = tid >> 6, lane = tid & 63;
    if (lane == 0) wmin[wave] = myMin;
    __syncthreads();
    if (tid == 0) {
        float m = fminf(fminf(wmin[0], wmin[1]), fminf(wmin[2], wmin[3]));
        float h = 1.0f - sqrtf(m);
        hinges[ci * K_CL + cj] = h > 0.0f ? h : 0.0f;
    }
}

__global__ void reduce_hinge_kernel(const float* __restrict__ hinges,
                                    float* __restrict__ out) {
    int tid = threadIdx.x;
    float s = 0.0f;
    for (int p = tid; p < K_CL * K_CL; p += 256) {
        int ci = p >> 6, cj = p & 63;
        if (ci < cj) s += hinges[p];
    }
    for (int off = 32; off > 0; off >>= 1)
        s += __shfl_down(s, off, 64);
    __shared__ float wsum[4];
    int wave = tid >> 6, lane = tid & 63;
    if (lane == 0) wsum[wave] = s;
    __syncthreads();
    if (tid == 0)
        out[0] = (wsum[0] + wsum[1] + wsum[2] + wsum[3]) / (float)NPAIR;
}

extern "C" void kernel_launch(void* const* d_in, const int* in_sizes, int n_in,
                              void* d_out, int out_size, void* d_ws, size_t ws_size,
                              hipStream_t stream) {
    const int*   labels = (const int*)d_in[1];     // cluster_labels (int32)
    const float* coords = (const float*)d_in[2];   // manifold_coords [8192,2] f32
    float* out = (float*)d_out;

    float2* lists  = (float2*)d_ws;                           // 192 KB
    int*    cnts   = (int*)((char*)d_ws + (size_t)K_CL * SEG * CAP_SEG * sizeof(float2));
    float*  hinges = (float*)((char*)cnts + K_CL * SEG * sizeof(int));

    dim3 ggrid(K_CL, SEG);
    gather_kernel<<<ggrid, 256, 0, stream>>>(labels, coords, lists, cnts);
    dim3 pgrid(K_CL, K_CL);
    pair_min_kernel<<<pgrid, 256, 0, stream>>>(lists, cnts, hinges);
    reduce_hinge_kernel<<<1, 256, 0, stream>>>(hinges, out);
}